// Round 8
// baseline (213.781 us; speedup 1.0000x reference)
//
#include <hip/hip_runtime.h>
#include <math.h>

static constexpr int BROWS   = 16384;
static constexpr int NC      = 784;
static constexpr int TRB     = 16;              // rows per tile/block
static constexpr int THREADS = 512;
static constexpr int NBLK    = BROWS / TRB;     // 1024 blocks
static constexpr int CHUNK   = 2;               // uint4 (16B) chunks per column (16 rows bf16)
static constexpr int REGN    = NC * CHUNK;      // 1568 uint4 per block region in global
static constexpr int NREP    = 4;               // replicated stat accumulators
static constexpr float EPS   = 1e-5f;
static constexpr float INV_B = 1.0f / (float)BROWS;

#if defined(__has_builtin)
#if __has_builtin(__builtin_amdgcn_rcpf)
#define HAVE_RCPF 1
#endif
#endif

// ---- bf16 helpers (raw u16 storage; RNE convert) ----
__device__ __forceinline__ unsigned short f2b(float f) {
    union { float f; unsigned u; } v; v.f = f;
    const unsigned r = v.u + 0x7fffu + ((v.u >> 16) & 1u);
    return (unsigned short)(r >> 16);
}
__device__ __forceinline__ unsigned pack2(float lo, float hi) {
    return (unsigned)f2b(lo) | ((unsigned)f2b(hi) << 16);
}
__device__ __forceinline__ float fast_rcp(float x) {
#ifdef HAVE_RCPF
    return __builtin_amdgcn_rcpf(x);
#else
    return 1.0f / x;
#endif
}
// Exact-accuracy gelu via A&S 7.1.26 erf (|eps| <= 1.5e-7), branchless. (validated R4/R6)
__device__ __forceinline__ float gelu_f(float x) {
    const float a = fabsf(x) * 0.7071067811865475f;
    const float t = fast_rcp(fmaf(0.3275911f, a, 1.0f));
    float p = fmaf(t, 1.061405429f, -1.453152027f);
    p = fmaf(t, p, 1.421413741f);
    p = fmaf(t, p, -0.284496736f);
    p = fmaf(t, p, 0.254829592f);
    p *= t;
    const float e  = __expf(-a * a);
    const float er = fmaf(-p, e, 1.0f);
    return 0.5f * x * (1.0f + copysignf(er, x));
}

// LDS tile layout: column c occupies uint4 slots 3c (rows 0..7) and 3c+1 (rows 8..15),
// slot 3c+2 is pad. Base bank-quad = (3c)%8, gcd(3,8)=1 => random c hits all 8 quads
// uniformly: every ds_read_b128 gather runs at the LDS BW floor, no pathological banking.
// u32 #q of a uint4 holds rows (8h+2q, 8h+2q+1) as (lo,hi) bf16.

__device__ __forceinline__ void fma8(const uint4 v, const float w, float acc[8]) {
    const unsigned* u = &v.x;
    #pragma unroll
    for (int q = 0; q < 4; ++q) {
        union { unsigned u; float f; } lo, hi;
        lo.u = u[q] << 16;
        hi.u = u[q] & 0xffff0000u;
        acc[2 * q]     = fmaf(lo.f, w, acc[2 * q]);
        acc[2 * q + 1] = fmaf(hi.f, w, acc[2 * q + 1]);
    }
}

// ---------------- K_A: fused L1 -> gelu -> L2 -> gelu (+ bn2a stats) ----------------
__global__ __launch_bounds__(THREADS, 6)
void k12(const float* __restrict__ x,
         const int* __restrict__ idx1, const float* __restrict__ W1, const float* __restrict__ b1,
         const int* __restrict__ idx2, const float* __restrict__ W2, const float* __restrict__ b2,
         uint4* __restrict__ outr, float* __restrict__ ssum, float* __restrict__ ssq)
{
    __shared__ uint4 tile[NC * 3];                 // 37632 B
    const int tid  = threadIdx.x;
    const int row0 = blockIdx.x * TRB;

    // ---- stage x (fp32 row-major) -> column-contiguous bf16 tile ----
    for (int c = tid; c < NC; c += THREADS) {
        float xr[TRB];
        #pragma unroll
        for (int r = 0; r < TRB; ++r) xr[r] = x[(size_t)(row0 + r) * NC + c];
        #pragma unroll
        for (int h = 0; h < 2; ++h) {
            uint4 v;
            v.x = pack2(xr[8 * h + 0], xr[8 * h + 1]);
            v.y = pack2(xr[8 * h + 2], xr[8 * h + 3]);
            v.z = pack2(xr[8 * h + 4], xr[8 * h + 5]);
            v.w = pack2(xr[8 * h + 6], xr[8 * h + 7]);
            tile[3 * c + h] = v;
        }
    }
    __syncthreads();

    // ---- L1 (K=2): compute into packed regs for both column slots ----
    unsigned hp0[2][4], hp1[2][4];
    const int j1 = tid + THREADS;
    const bool act1 = (j1 < NC);
    {
        const int   c0 = idx1[2 * tid], c1 = idx1[2 * tid + 1];
        const float w0 = W1[2 * tid],   w1 = W1[2 * tid + 1], bb = b1[tid];
        #pragma unroll
        for (int h = 0; h < 2; ++h) {
            float acc[8];
            #pragma unroll
            for (int r = 0; r < 8; ++r) acc[r] = bb;
            fma8(tile[3 * c0 + h], w0, acc);
            fma8(tile[3 * c1 + h], w1, acc);
            #pragma unroll
            for (int q = 0; q < 4; ++q)
                hp0[h][q] = pack2(gelu_f(acc[2 * q]), gelu_f(acc[2 * q + 1]));
        }
    }
    if (act1) {
        const int   c0 = idx1[2 * j1], c1 = idx1[2 * j1 + 1];
        const float w0 = W1[2 * j1],   w1 = W1[2 * j1 + 1], bb = b1[j1];
        #pragma unroll
        for (int h = 0; h < 2; ++h) {
            float acc[8];
            #pragma unroll
            for (int r = 0; r < 8; ++r) acc[r] = bb;
            fma8(tile[3 * c0 + h], w0, acc);
            fma8(tile[3 * c1 + h], w1, acc);
            #pragma unroll
            for (int q = 0; q < 4; ++q)
                hp1[h][q] = pack2(gelu_f(acc[2 * q]), gelu_f(acc[2 * q + 1]));
        }
    }
    __syncthreads();          // all L1 gathers done
    #pragma unroll
    for (int h = 0; h < 2; ++h) {
        tile[3 * tid + h] = make_uint4(hp0[h][0], hp0[h][1], hp0[h][2], hp0[h][3]);
        if (act1)
            tile[3 * j1 + h] = make_uint4(hp1[h][0], hp1[h][1], hp1[h][2], hp1[h][3]);
    }
    __syncthreads();          // h1 tile ready

    // ---- L2 (K=4) + gelu + stats + packed global store ----
    const int rep = blockIdx.x & (NREP - 1);
    uint4* dst = outr + (size_t)blockIdx.x * REGN;
    for (int j = tid; j < NC; j += THREADS) {
        int ji[4]; float jw[4];
        #pragma unroll
        for (int k = 0; k < 4; ++k) { ji[k] = idx2[4 * j + k]; jw[k] = W2[4 * j + k]; }
        const float jb = b2[j];
        float s1 = 0.0f, s2 = 0.0f;
        #pragma unroll
        for (int h = 0; h < 2; ++h) {
            float acc[8];
            #pragma unroll
            for (int r = 0; r < 8; ++r) acc[r] = jb;
            #pragma unroll
            for (int k = 0; k < 4; ++k) fma8(tile[3 * ji[k] + h], jw[k], acc);
            unsigned up[4];
            #pragma unroll
            for (int q = 0; q < 4; ++q) {
                const float ulo = gelu_f(acc[2 * q]), uhi = gelu_f(acc[2 * q + 1]);
                s1 += ulo + uhi; s2 = fmaf(ulo, ulo, fmaf(uhi, uhi, s2));
                up[q] = pack2(ulo, uhi);
            }
            dst[2 * j + h] = make_uint4(up[0], up[1], up[2], up[3]);
        }
        atomicAdd(&ssum[rep * NC + j], s1);
        atomicAdd(&ssq[rep * NC + j],  s2);
    }
}

// -------- K_B/C/D: fold prev BN into weights -> sparse -> act (+ stats) --------
template<int K, bool FINAL>
__global__ __launch_bounds__(THREADS, 6)
void kbn(const uint4* __restrict__ inr,
         const int* __restrict__ idx, const float* __restrict__ W, const float* __restrict__ bias,
         const float* __restrict__ gamma, const float* __restrict__ beta,
         const float* __restrict__ psum, const float* __restrict__ psq,
         uint4* __restrict__ outr, float* __restrict__ fout,
         float* __restrict__ ssum, float* __restrict__ ssq)
{
    __shared__ uint4 tile[NC * 3];                 // 37632 B
    __shared__ float s_sc[NC], s_sh[NC];           //  6272 B
    const int tid  = threadIdx.x;
    const int row0 = blockIdx.x * TRB;

    // issue the staging loads first (VGPR route; swizzled ds_write below)
    const uint4* src = inr + (size_t)blockIdx.x * REGN;
    uint4 sv[4];
    #pragma unroll
    for (int t = 0; t < 4; ++t) {
        const int e = tid + t * THREADS;
        if (e < REGN) sv[t] = src[e];
    }
    // finalize previous BN into scale/shift (L2-hot; overlaps the loads above)
    for (int j = tid; j < NC; j += THREADS) {
        float s1 = 0.0f, s2 = 0.0f;
        #pragma unroll
        for (int r = 0; r < NREP; ++r) { s1 += psum[r * NC + j]; s2 += psq[r * NC + j]; }
        const float m   = s1 * INV_B;
        const float var = fmaf(-m, m, s2 * INV_B);
        const float sc  = gamma[j] * rsqrtf(var + EPS);
        s_sc[j] = sc;
        s_sh[j] = fmaf(-m, sc, beta[j]);
    }
    #pragma unroll
    for (int t = 0; t < 4; ++t) {
        const int e = tid + t * THREADS;
        if (e < REGN) tile[3 * (e >> 1) + (e & 1)] = sv[t];
    }
    __syncthreads();

    const int rep = blockIdx.x & (NREP - 1);
    uint4* dst = FINAL ? nullptr : (outr + (size_t)blockIdx.x * REGN);
    for (int j = tid; j < NC; j += THREADS) {
        int ji[K]; float jw[K];
        float jb = bias[j];
        #pragma unroll
        for (int k = 0; k < K; ++k) {
            const int   c = idx[K * j + k];
            const float w = W[K * j + k];
            ji[k] = c; jw[k] = w * s_sc[c]; jb = fmaf(w, s_sh[c], jb);
        }
        float s1 = 0.0f, s2 = 0.0f;
        #pragma unroll
        for (int h = 0; h < 2; ++h) {
            float acc[8];
            #pragma unroll
            for (int r = 0; r < 8; ++r) acc[r] = jb;
            #pragma unroll
            for (int k = 0; k < K; ++k) fma8(tile[3 * ji[k] + h], jw[k], acc);
            if (FINAL) {
                #pragma unroll
                for (int r = 0; r < 8; ++r)
                    fout[(size_t)(row0 + 8 * h + r) * NC + j] = fmaxf(acc[r], 0.0f);
            } else {
                unsigned up[4];
                #pragma unroll
                for (int q = 0; q < 4; ++q) {
                    const float ulo = gelu_f(acc[2 * q]), uhi = gelu_f(acc[2 * q + 1]);
                    s1 += ulo + uhi; s2 = fmaf(ulo, ulo, fmaf(uhi, uhi, s2));
                    up[q] = pack2(ulo, uhi);
                }
                dst[2 * j + h] = make_uint4(up[0], up[1], up[2], up[3]);
            }
        }
        if (!FINAL) {
            atomicAdd(&ssum[rep * NC + j], s1);
            atomicAdd(&ssq[rep * NC + j],  s2);
        }
    }
}

extern "C" void kernel_launch(void* const* d_in, const int* in_sizes, int n_in,
                              void* d_out, int out_size, void* d_ws, size_t ws_size,
                              hipStream_t stream)
{
    const float* x    = (const float*)d_in[0];
    const int*   idx1 = (const int*)  d_in[1];
    const float* W1   = (const float*)d_in[2];
    const float* b1   = (const float*)d_in[3];
    const int*   idx2 = (const int*)  d_in[4];
    const float* W2   = (const float*)d_in[5];
    const float* b2   = (const float*)d_in[6];
    const int*   idx3 = (const int*)  d_in[7];
    const float* W3   = (const float*)d_in[8];
    const float* b3   = (const float*)d_in[9];
    const float* g2   = (const float*)d_in[10];
    const float* be2  = (const float*)d_in[11];
    const float* g3   = (const float*)d_in[12];
    const float* be3  = (const float*)d_in[13];
    float* out = (float*)d_out;

    // Packed-chunk bf16 ping-pong regions:
    //   K_A: r x   -> w r0 (u2)
    //   K_B: r r0  -> w r1 (u3)
    //   K_C: r r1  -> w r0 (u4; u2 dead)
    //   K_D: r r0  -> w out (fp32 row-major)
    uint4* r0 = (uint4*)d_ws;
    uint4* r1 = r0 + (size_t)NBLK * REGN;
    float* p  = (float*)(r1 + (size_t)NBLK * REGN);
    float* sum2a = p; p += NREP * NC;  float* ssq2a = p; p += NREP * NC;
    float* sum3  = p; p += NREP * NC;  float* ssq3  = p; p += NREP * NC;
    float* sum2b = p; p += NREP * NC;  float* ssq2b = p; p += NREP * NC;

    hipMemsetAsync(sum2a, 0, 6 * NREP * NC * sizeof(float), stream);

    const dim3 grid(NBLK), blk(THREADS);

    k12<<<grid, blk, 0, stream>>>(x, idx1, W1, b1, idx2, W2, b2, r0, sum2a, ssq2a);
    kbn<8, false><<<grid, blk, 0, stream>>>(
        r0, idx3, W3, b3, g2, be2, sum2a, ssq2a, r1, nullptr, sum3, ssq3);
    kbn<4, false><<<grid, blk, 0, stream>>>(
        r1, idx2, W2, b2, g3, be3, sum3, ssq3, r0, nullptr, sum2b, ssq2b);
    kbn<2, true><<<grid, blk, 0, stream>>>(
        r0, idx1, W1, b1, g2, be2, sum2b, ssq2b, nullptr, out, nullptr, nullptr);
}

// Round 9
// 186.595 us; speedup vs baseline: 1.1457x; 1.1457x over previous
//
#include <hip/hip_runtime.h>
#include <math.h>

static constexpr int BROWS   = 16384;
static constexpr int NC      = 784;
static constexpr int TRB     = 16;              // rows per tile/block
static constexpr int THREADS = 512;
static constexpr int NBLK    = BROWS / TRB;     // 1024 blocks
static constexpr int NSLOT   = 2;               // ceil(784/512) column slots per thread
static constexpr int NREP    = 4;               // replicated stat accumulators
static constexpr float EPS   = 1e-5f;
static constexpr float INV_B = 1.0f / (float)BROWS;

#if defined(__has_builtin)
#if __has_builtin(__builtin_amdgcn_global_load_lds)
#define HAVE_ASYNC_LDS 1
#endif
#if __has_builtin(__builtin_amdgcn_rcpf)
#define HAVE_RCPF 1
#endif
#if __has_builtin(__builtin_elementwise_fma)
#define HAVE_EW_FMA 1
#endif
#endif

typedef float v2f __attribute__((ext_vector_type(2)));

__device__ __forceinline__ void stage16(const float4* g, float4* l) {
#ifdef HAVE_ASYNC_LDS
    __builtin_amdgcn_global_load_lds(
        (const __attribute__((address_space(1))) void*)g,
        (__attribute__((address_space(3))) void*)l, 16, 0, 0);
#else
    *l = *g;
#endif
}

// ---- bf16 helpers (raw u16 storage; RNE convert) ----
__device__ __forceinline__ unsigned short f2b(float f) {
    union { float f; unsigned u; } v; v.f = f;
    const unsigned r = v.u + 0x7fffu + ((v.u >> 16) & 1u);
    return (unsigned short)(r >> 16);
}
__device__ __forceinline__ unsigned pack2(float lo, float hi) {
    return (unsigned)f2b(lo) | ((unsigned)f2b(hi) << 16);
}
__device__ __forceinline__ unsigned long long pack4(float a, float b, float c, float d) {
    return (unsigned long long)pack2(a, b) | ((unsigned long long)pack2(c, d) << 32);
}
__device__ __forceinline__ float fast_rcp(float x) {
#ifdef HAVE_RCPF
    return __builtin_amdgcn_rcpf(x);
#else
    return 1.0f / x;
#endif
}

// tanh-form gelu (max |err| ~3e-4, far under the 0.2625 budget), ~9 VALU ops,
// branchless, correct limits: x->+inf => x, x->-inf => 0.
__device__ __forceinline__ float gelu_f(float x) {
    const float u  = x * x;
    const float z  = x * fmaf(0.0356774081f, u, 0.7978845608f);
    const float e  = __expf(2.0f * z);            // e^{2z}
    const float r  = fast_rcp(e + 1.0f);
    const float t  = fmaf(-2.0f, r, 1.0f);        // tanh(z)
    const float hx = 0.5f * x;
    return fmaf(hx, t, hx);
}

// u64 = 4 bf16 rows of one column (rows 4q..4q+3). Unpack to 2x v2f and FMA
// with packed v_pk_fma_f32: 6 VALU ops per quad instead of 8 scalar.
__device__ __forceinline__ void fmaq(const unsigned long long v, const float w, v2f acc[2]) {
    const unsigned lo = (unsigned)v, hi = (unsigned)(v >> 32);
    union { unsigned u; float f; } a0, a1, b0, b1;
    a0.u = lo << 16; a1.u = lo & 0xffff0000u;
    b0.u = hi << 16; b1.u = hi & 0xffff0000u;
    const v2f a = { a0.f, a1.f }, b = { b0.f, b1.f };
    const v2f w2 = { w, w };
#ifdef HAVE_EW_FMA
    acc[0] = __builtin_elementwise_fma(a, w2, acc[0]);
    acc[1] = __builtin_elementwise_fma(b, w2, acc[1]);
#else
    acc[0] += a * w2;
    acc[1] += b * w2;
#endif
}

// ---------------- K_A: fused L1 -> gelu -> L2 -> gelu (+ bn2a stats) ----------------
// x staged to quad-u64 bf16 tileX; L1 reads tileX / writes tileH (no in-place hazard,
// 2 barriers total); L2 gathers tileH, stores quad region to global.
__global__ __launch_bounds__(THREADS, 6)
void k12(const float* __restrict__ x,
         const int* __restrict__ idx1, const float* __restrict__ W1, const float* __restrict__ b1,
         const int* __restrict__ idx2, const float* __restrict__ W2, const float* __restrict__ b2,
         unsigned long long* __restrict__ outr,
         float* __restrict__ ssum, float* __restrict__ ssq)
{
    __shared__ unsigned long long tileX[4 * NC];   // 25088 B
    __shared__ unsigned long long tileH[4 * NC];   // 25088 B
    const int tid  = threadIdx.x;
    const int row0 = blockIdx.x * TRB;

    // stage x (fp32 row-major) -> quad bf16 tileX (coalesced dword reads per row)
    #pragma unroll
    for (int slot = 0; slot < NSLOT; ++slot) {
        const int c = tid + slot * THREADS;
        if (c < NC) {
            #pragma unroll
            for (int q = 0; q < 4; ++q) {
                const size_t base = (size_t)(row0 + 4 * q) * NC + c;
                tileX[q * NC + c] = pack4(x[base], x[base + NC], x[base + 2 * NC], x[base + 3 * NC]);
            }
        }
    }
    __syncthreads();

    // L1 (K=2): tileX -> tileH
    #pragma unroll
    for (int slot = 0; slot < NSLOT; ++slot) {
        const int j = tid + slot * THREADS;
        if (j < NC) {
            const int   c0 = idx1[2 * j], c1 = idx1[2 * j + 1];
            const float w0 = W1[2 * j],   w1 = W1[2 * j + 1], bb = b1[j];
            #pragma unroll
            for (int q = 0; q < 4; ++q) {
                v2f acc[2] = { { bb, bb }, { bb, bb } };
                fmaq(tileX[q * NC + c0], w0, acc);
                fmaq(tileX[q * NC + c1], w1, acc);
                tileH[q * NC + j] = pack4(gelu_f(acc[0].x), gelu_f(acc[0].y),
                                          gelu_f(acc[1].x), gelu_f(acc[1].y));
            }
        }
    }
    __syncthreads();

    // L2 (K=4) + gelu + stats + quad global store
    const int rep = blockIdx.x & (NREP - 1);
    unsigned long long* dst = outr + (size_t)blockIdx.x * 4 * NC;
    #pragma unroll
    for (int slot = 0; slot < NSLOT; ++slot) {
        const int j = tid + slot * THREADS;
        if (j < NC) {
            int ji[4]; float jw[4];
            #pragma unroll
            for (int k = 0; k < 4; ++k) { ji[k] = idx2[4 * j + k]; jw[k] = W2[4 * j + k]; }
            const float jb = b2[j];
            float s1 = 0.0f, s2 = 0.0f;
            #pragma unroll
            for (int q = 0; q < 4; ++q) {
                v2f acc[2] = { { jb, jb }, { jb, jb } };
                #pragma unroll
                for (int k = 0; k < 4; ++k) fmaq(tileH[q * NC + ji[k]], jw[k], acc);
                const float u0 = gelu_f(acc[0].x), u1 = gelu_f(acc[0].y);
                const float u2 = gelu_f(acc[1].x), u3 = gelu_f(acc[1].y);
                s1 += (u0 + u1) + (u2 + u3);
                s2 = fmaf(u0, u0, fmaf(u1, u1, fmaf(u2, u2, fmaf(u3, u3, s2))));
                dst[q * NC + j] = pack4(u0, u1, u2, u3);
            }
            atomicAdd(&ssum[rep * NC + j], s1);
            atomicAdd(&ssq[rep * NC + j],  s2);
        }
    }
}

// -------- K_B/C/D: fold prev BN into weights -> sparse -> act (+ stats) --------
template<int K, bool FINAL>
__global__ __launch_bounds__(THREADS, 8)
void kbn(const unsigned long long* __restrict__ inr,
         const int* __restrict__ idx, const float* __restrict__ W, const float* __restrict__ bias,
         const float* __restrict__ gamma, const float* __restrict__ beta,
         const float* __restrict__ psum, const float* __restrict__ psq,
         unsigned long long* __restrict__ outr, float* __restrict__ fout,
         float* __restrict__ ssum, float* __restrict__ ssq)
{
    __shared__ unsigned long long tile[4 * NC];    // 25088 B
    __shared__ float s_sc[NC], s_sh[NC];           //  6272 B
    const int tid  = threadIdx.x;
    const int row0 = blockIdx.x * TRB;

    {   // async DMA of the contiguous quad region (lane-linear dst)
        const float4* src = (const float4*)(inr + (size_t)blockIdx.x * 4 * NC);
        float4*       dstl = (float4*)tile;
        for (int i = tid; i < 4 * NC / 2; i += THREADS) stage16(src + i, dstl + i);
    }
    // finalize previous BN into scale/shift (L2-hot; overlaps the DMA)
    for (int j = tid; j < NC; j += THREADS) {
        float s1 = 0.0f, s2 = 0.0f;
        #pragma unroll
        for (int r = 0; r < NREP; ++r) { s1 += psum[r * NC + j]; s2 += psq[r * NC + j]; }
        const float m   = s1 * INV_B;
        const float var = fmaf(-m, m, s2 * INV_B);
        const float sc  = gamma[j] * rsqrtf(var + EPS);
        s_sc[j] = sc;
        s_sh[j] = fmaf(-m, sc, beta[j]);
    }
    __syncthreads();   // drains DMA + publishes sc/sh

    const int rep = blockIdx.x & (NREP - 1);
    unsigned long long* dst = FINAL ? nullptr : (outr + (size_t)blockIdx.x * 4 * NC);
    #pragma unroll
    for (int slot = 0; slot < NSLOT; ++slot) {
        const int j = tid + slot * THREADS;
        if (j < NC) {
            int ji[K]; float jw[K];
            float jb = bias[j];
            #pragma unroll
            for (int k = 0; k < K; ++k) {
                const int   c = idx[K * j + k];
                const float w = W[K * j + k];
                ji[k] = c; jw[k] = w * s_sc[c]; jb = fmaf(w, s_sh[c], jb);
            }
            float s1 = 0.0f, s2 = 0.0f;
            #pragma unroll
            for (int q = 0; q < 4; ++q) {
                v2f acc[2] = { { jb, jb }, { jb, jb } };
                #pragma unroll
                for (int k = 0; k < K; ++k) fmaq(tile[q * NC + ji[k]], jw[k], acc);
                if (FINAL) {
                    fout[(size_t)(row0 + 4 * q + 0) * NC + j] = fmaxf(acc[0].x, 0.0f);
                    fout[(size_t)(row0 + 4 * q + 1) * NC + j] = fmaxf(acc[0].y, 0.0f);
                    fout[(size_t)(row0 + 4 * q + 2) * NC + j] = fmaxf(acc[1].x, 0.0f);
                    fout[(size_t)(row0 + 4 * q + 3) * NC + j] = fmaxf(acc[1].y, 0.0f);
                } else {
                    const float u0 = gelu_f(acc[0].x), u1 = gelu_f(acc[0].y);
                    const float u2 = gelu_f(acc[1].x), u3 = gelu_f(acc[1].y);
                    s1 += (u0 + u1) + (u2 + u3);
                    s2 = fmaf(u0, u0, fmaf(u1, u1, fmaf(u2, u2, fmaf(u3, u3, s2))));
                    dst[q * NC + j] = pack4(u0, u1, u2, u3);
                }
            }
            if (!FINAL) {
                atomicAdd(&ssum[rep * NC + j], s1);
                atomicAdd(&ssq[rep * NC + j],  s2);
            }
        }
    }
}

extern "C" void kernel_launch(void* const* d_in, const int* in_sizes, int n_in,
                              void* d_out, int out_size, void* d_ws, size_t ws_size,
                              hipStream_t stream)
{
    const float* x    = (const float*)d_in[0];
    const int*   idx1 = (const int*)  d_in[1];
    const float* W1   = (const float*)d_in[2];
    const float* b1   = (const float*)d_in[3];
    const int*   idx2 = (const int*)  d_in[4];
    const float* W2   = (const float*)d_in[5];
    const float* b2   = (const float*)d_in[6];
    const int*   idx3 = (const int*)  d_in[7];
    const float* W3   = (const float*)d_in[8];
    const float* b3   = (const float*)d_in[9];
    const float* g2   = (const float*)d_in[10];
    const float* be2  = (const float*)d_in[11];
    const float* g3   = (const float*)d_in[12];
    const float* be3  = (const float*)d_in[13];
    float* out = (float*)d_out;

    const size_t QN = (size_t)NBLK * 4 * NC;       // u64 elems per intermediate
    // Quad-layout bf16 ping-pong:
    //   k12      : r x  -> w r0 (u2)
    //   kbn<8>   : r r0 -> w r1 (u3)
    //   kbn<4>   : r r1 -> w r0 (u4; u2 dead)
    //   kbn<2,F> : r r0 -> w out (fp32 row-major)
    unsigned long long* r0 = (unsigned long long*)d_ws;
    unsigned long long* r1 = r0 + QN;
    float* p = (float*)(r1 + QN);
    float* sum2a = p; p += NREP * NC;  float* ssq2a = p; p += NREP * NC;
    float* sum3  = p; p += NREP * NC;  float* ssq3  = p; p += NREP * NC;
    float* sum2b = p; p += NREP * NC;  float* ssq2b = p; p += NREP * NC;

    hipMemsetAsync(sum2a, 0, 6 * NREP * NC * sizeof(float), stream);

    const dim3 grid(NBLK), blk(THREADS);

    k12<<<grid, blk, 0, stream>>>(x, idx1, W1, b1, idx2, W2, b2, r0, sum2a, ssq2a);
    kbn<8, false><<<grid, blk, 0, stream>>>(
        r0, idx3, W3, b3, g2, be2, sum2a, ssq2a, r1, nullptr, sum3, ssq3);
    kbn<4, false><<<grid, blk, 0, stream>>>(
        r1, idx2, W2, b2, g3, be3, sum3, ssq3, r0, nullptr, sum2b, ssq2b);
    kbn<2, true><<<grid, blk, 0, stream>>>(
        r0, idx1, W1, b1, g2, be2, sum2b, ssq2b, nullptr, out, nullptr, nullptr);
}